// Round 1
// baseline (155.294 us; speedup 1.0000x reference)
//
#include <hip/hip_runtime.h>
#include <hip/hip_bf16.h>
#include <math.h>

#define NPAIR 4096       // N = B*S
#define D 128
#define TWO_N 8192
#define INV_T 2.0f       // 1 / 0.5

typedef short bf16x8 __attribute__((ext_vector_type(8)));
typedef float f32x4 __attribute__((ext_vector_type(4)));

__device__ inline unsigned short f2bf(float x) {
    union { float f; unsigned u; } v; v.f = x;
    unsigned u = v.u;
    unsigned r = u + 0x7fffu + ((u >> 16) & 1u);   // round-to-nearest-even
    return (unsigned short)(r >> 16);
}

// One wave per pair-row k: normalize zi_k, zj_k (fp32), emit bf16 rows k and k+N,
// and pos[k] = <zi_k, zj_k> / (|zi_k||zj_k|) in exact fp32.
__global__ __launch_bounds__(64) void norm_kernel(const float* __restrict__ zi,
                                                  const float* __restrict__ zj,
                                                  unsigned int* __restrict__ Rb,
                                                  float* __restrict__ pos) {
    int k = blockIdx.x;
    int t = threadIdx.x;                  // 0..63, 2 elems each
    const float2 a = *(const float2*)(zi + k * D + 2 * t);
    const float2 b = *(const float2*)(zj + k * D + 2 * t);
    float si = a.x * a.x + a.y * a.y;
    float sj = b.x * b.x + b.y * b.y;
    float dt = a.x * b.x + a.y * b.y;
    #pragma unroll
    for (int m = 1; m < 64; m <<= 1) {
        si += __shfl_xor(si, m, 64);
        sj += __shfl_xor(sj, m, 64);
        dt += __shfl_xor(dt, m, 64);
    }
    float ii = 1.0f / fmaxf(sqrtf(si), 1e-12f);
    float ij = 1.0f / fmaxf(sqrtf(sj), 1e-12f);
    unsigned short b0 = f2bf(a.x * ii), b1 = f2bf(a.y * ii);
    Rb[k * (D / 2) + t] = (unsigned)b0 | ((unsigned)b1 << 16);
    b0 = f2bf(b.x * ij); b1 = f2bf(b.y * ij);
    Rb[(k + NPAIR) * (D / 2) + t] = (unsigned)b0 | ((unsigned)b1 << 16);
    if (t == 0) pos[k] = dt * ii * ij;
}

// Tile (bi,bj): sim block = Ri(128xK) * Rj(128xK)^T via bf16 MFMA; accumulate
// rowsum[row] += sum_cols exp(sim*2), excluding the exact diagonal row==col.
__global__ __launch_bounds__(256) void simexp_kernel(const uint4* __restrict__ Rb,
                                                     float* __restrict__ rowsum) {
    // chunk-major LDS: [kchunk(16)][row(128)] of uint4 (8 bf16 each)
    __shared__ uint4 As[16 * 128];
    __shared__ uint4 Bs[16 * 128];
    const int bi = blockIdx.y, bj = blockIdx.x;
    const int tid = threadIdx.x;

    #pragma unroll
    for (int it = 0; it < 8; ++it) {
        int slot = it * 256 + tid;
        int row = (slot & 15) + ((slot >> 8) << 4);   // 0..127
        int c = (slot >> 4) & 15;                     // 0..15
        As[c * 128 + row] = Rb[(bi * 128 + row) * 16 + c];
        Bs[c * 128 + row] = Rb[(bj * 128 + row) * 16 + c];
    }
    __syncthreads();

    const int wave = tid >> 6, lane = tid & 63;
    const int rp = lane & 15, q = lane >> 4;
    const int wr = (wave & 1) * 64;     // this wave's row quadrant
    const int wc = (wave >> 1) * 64;    // this wave's col quadrant

    f32x4 acc[4][4] = {};
    #pragma unroll
    for (int kt = 0; kt < 4; ++kt) {
        bf16x8 afr[4], bfr[4];
        const int cb = (kt * 4 + q) * 128;
        #pragma unroll
        for (int rt = 0; rt < 4; ++rt)
            afr[rt] = *(const bf16x8*)&As[cb + wr + rt * 16 + rp];
        #pragma unroll
        for (int ct = 0; ct < 4; ++ct)
            bfr[ct] = *(const bf16x8*)&Bs[cb + wc + ct * 16 + rp];
        #pragma unroll
        for (int rt = 0; rt < 4; ++rt)
            #pragma unroll
            for (int ct = 0; ct < 4; ++ct)
                acc[rt][ct] = __builtin_amdgcn_mfma_f32_16x16x32_bf16(
                    afr[rt], bfr[ct], acc[rt][ct], 0, 0, 0);
    }

    // Epilogue: D layout col = lane&15, row = q*4 + reg
    const int grow_base = bi * 128 + wr + q * 4;
    const int gcol_base = bj * 128 + wc + rp;
    #pragma unroll
    for (int rt = 0; rt < 4; ++rt) {
        #pragma unroll
        for (int r = 0; r < 4; ++r) {
            int grow = grow_base + rt * 16 + r;
            float partial = 0.f;
            #pragma unroll
            for (int ct = 0; ct < 4; ++ct) {
                int gcol = gcol_base + ct * 16;
                float e = __expf(acc[rt][ct][r] * INV_T);
                partial += (grow == gcol) ? 0.f : e;
            }
            partial += __shfl_xor(partial, 1, 64);
            partial += __shfl_xor(partial, 2, 64);
            partial += __shfl_xor(partial, 4, 64);
            partial += __shfl_xor(partial, 8, 64);
            if (rp == 0) atomicAdd(&rowsum[grow], partial);
        }
    }
}

__global__ __launch_bounds__(256) void finalize_kernel(const float* __restrict__ rowsum,
                                                       const float* __restrict__ pos,
                                                       float* __restrict__ out) {
    __shared__ float red[4];
    int tid = threadIdx.x;
    float local = 0.f;
    for (int k = tid; k < TWO_N; k += 256) {
        float p = pos[k & (NPAIR - 1)];
        float denom = rowsum[k] + __expf(p * INV_T);
        local += logf(denom) - p * INV_T;
    }
    #pragma unroll
    for (int m = 1; m < 64; m <<= 1) local += __shfl_xor(local, m, 64);
    if ((tid & 63) == 0) red[tid >> 6] = local;
    __syncthreads();
    if (tid == 0) out[0] = (red[0] + red[1] + red[2] + red[3]) / (float)TWO_N;
}

extern "C" void kernel_launch(void* const* d_in, const int* in_sizes, int n_in,
                              void* d_out, int out_size, void* d_ws, size_t ws_size,
                              hipStream_t stream) {
    const float* zi = (const float*)d_in[0];
    const float* zj = (const float*)d_in[1];
    char* ws = (char*)d_ws;
    unsigned int* Rb = (unsigned int*)ws;                          // 8192*128*2 = 2 MB bf16
    float* rowsum = (float*)(ws + 2 * 1024 * 1024);                // 32 KB
    float* pos = (float*)(ws + 2 * 1024 * 1024 + 32 * 1024);       // 16 KB

    hipMemsetAsync(rowsum, 0, TWO_N * sizeof(float), stream);
    norm_kernel<<<NPAIR, 64, 0, stream>>>(zi, zj, Rb, pos);
    simexp_kernel<<<dim3(64, 64), 256, 0, stream>>>((const uint4*)Rb, rowsum);
    finalize_kernel<<<1, 256, 0, stream>>>(rowsum, pos, (float*)d_out);
}

// Round 3
// 92.379 us; speedup vs baseline: 1.6810x; 1.6810x over previous
//
#include <hip/hip_runtime.h>
#include <hip/hip_bf16.h>
#include <math.h>

#define NPAIR 4096       // N = B*S
#define D 128
#define TWO_N 8192
#define NJC 8            // col-slab splits; each block covers 1024 cols
#define NPART (NJC * 2)  // two col-half waves per block store separately

typedef short bf16x8 __attribute__((ext_vector_type(8)));
typedef float f32x4 __attribute__((ext_vector_type(4)));

__device__ inline unsigned short f2bf(float x) {
    union { float f; unsigned u; } v; v.f = x;
    unsigned u = v.u;
    unsigned r = u + 0x7fffu + ((u >> 16) & 1u);   // round-to-nearest-even
    return (unsigned short)(r >> 16);
}

// 1024 blocks x 256 threads; wave w handles pair-row k = blockIdx*4 + w.
__global__ __launch_bounds__(256) void norm_kernel(const float* __restrict__ zi,
                                                   const float* __restrict__ zj,
                                                   unsigned int* __restrict__ Rb,
                                                   float* __restrict__ pos) {
    int k = blockIdx.x * 4 + (threadIdx.x >> 6);
    int t = threadIdx.x & 63;                 // 2 elems each
    const float2 a = *(const float2*)(zi + k * D + 2 * t);
    const float2 b = *(const float2*)(zj + k * D + 2 * t);
    float si = a.x * a.x + a.y * a.y;
    float sj = b.x * b.x + b.y * b.y;
    float dt = a.x * b.x + a.y * b.y;
    #pragma unroll
    for (int m = 1; m < 64; m <<= 1) {
        si += __shfl_xor(si, m, 64);
        sj += __shfl_xor(sj, m, 64);
        dt += __shfl_xor(dt, m, 64);
    }
    float ii = 1.0f / fmaxf(sqrtf(si), 1e-12f);
    float ij = 1.0f / fmaxf(sqrtf(sj), 1e-12f);
    unsigned short b0 = f2bf(a.x * ii), b1 = f2bf(a.y * ii);
    Rb[k * (D / 2) + t] = (unsigned)b0 | ((unsigned)b1 << 16);
    b0 = f2bf(b.x * ij); b1 = f2bf(b.y * ij);
    Rb[(k + NPAIR) * (D / 2) + t] = (unsigned)b0 | ((unsigned)b1 << 16);
    if (t == 0) pos[k] = dt * ii * ij;
}

// 512 blocks: bi = b>>3 (row stripe of 128), jc = b&7 (col slab of 1024).
// Loops 8 col-tiles; accumulates sum_cols exp(2*sim) in 16 regs/lane;
// one cross-lane reduce + plain store per block. Waves 0/2 (and 1/3) share
// rows but cover different col halves -> they store to SEPARATE partial
// slabs (index jc*2 + (wave>>1)) to avoid the R1 overwrite race.
__global__ __launch_bounds__(256, 2) void simexp_kernel(const uint4* __restrict__ Rb,
                                                        float* __restrict__ rspart) {
    __shared__ uint4 As[16 * 128];   // chunk-major: [c][row]
    __shared__ uint4 Bs[16 * 128];
    const int bi = blockIdx.x >> 3, jc = blockIdx.x & 7;
    const int tid = threadIdx.x;

    #pragma unroll
    for (int it = 0; it < 8; ++it) {
        int slot = it * 256 + tid;
        int row = (slot & 15) + ((slot >> 8) << 4);
        int c = (slot >> 4) & 15;
        As[c * 128 + row] = Rb[(bi * 128 + row) * 16 + c];
    }

    const int wave = tid >> 6, lane = tid & 63;
    const int rp = lane & 15, q = lane >> 4;
    const int wr = (wave & 1) * 64;     // row quadrant
    const int wc = (wave >> 1) * 64;    // col quadrant

    float rs[16];
    #pragma unroll
    for (int i = 0; i < 16; ++i) rs[i] = 0.f;

    for (int jt = 0; jt < 8; ++jt) {
        const int colbase = jc * 1024 + jt * 128;
        __syncthreads();   // jt=0: orders A writes; jt>0: protects Bs reuse
        #pragma unroll
        for (int it = 0; it < 8; ++it) {
            int slot = it * 256 + tid;
            int row = (slot & 15) + ((slot >> 8) << 4);
            int c = (slot >> 4) & 15;
            Bs[c * 128 + row] = Rb[(colbase + row) * 16 + c];
        }
        __syncthreads();

        f32x4 acc[4][4] = {};
        #pragma unroll
        for (int kt = 0; kt < 4; ++kt) {
            bf16x8 afr[4], bfr[4];
            const int cb = (kt * 4 + q) * 128;
            #pragma unroll
            for (int rt = 0; rt < 4; ++rt)
                afr[rt] = *(const bf16x8*)&As[cb + wr + rt * 16 + rp];
            #pragma unroll
            for (int ct = 0; ct < 4; ++ct)
                bfr[ct] = *(const bf16x8*)&Bs[cb + wc + ct * 16 + rp];
            #pragma unroll
            for (int rt = 0; rt < 4; ++rt)
                #pragma unroll
                for (int ct = 0; ct < 4; ++ct)
                    acc[rt][ct] = __builtin_amdgcn_mfma_f32_16x16x32_bf16(
                        afr[rt], bfr[ct], acc[rt][ct], 0, 0, 0);
        }

        // D layout: col = lane&15 (rp), row = q*4 + reg
        if (colbase == bi * 128) {         // diagonal tile (wave-uniform branch)
            #pragma unroll
            for (int rt = 0; rt < 4; ++rt)
                #pragma unroll
                for (int r = 0; r < 4; ++r) {
                    int ro = wr + q * 4 + rt * 16 + r;   // stripe-local row
                    float s = 0.f;
                    #pragma unroll
                    for (int ct = 0; ct < 4; ++ct) {
                        int co = wc + ct * 16 + rp;
                        float x = acc[rt][ct][r];
                        float e = __expf(x + x);
                        s += (ro == co) ? 0.f : e;
                    }
                    rs[rt * 4 + r] += s;
                }
        } else {
            #pragma unroll
            for (int rt = 0; rt < 4; ++rt)
                #pragma unroll
                for (int r = 0; r < 4; ++r) {
                    float s = 0.f;
                    #pragma unroll
                    for (int ct = 0; ct < 4; ++ct) {
                        float x = acc[rt][ct][r];
                        s += __expf(x + x);
                    }
                    rs[rt * 4 + r] += s;
                }
        }
    }

    // Once per block: reduce each reg across the 16 rp lanes, store.
    #pragma unroll
    for (int i = 0; i < 16; ++i) {
        float v = rs[i];
        v += __shfl_xor(v, 1, 64);
        v += __shfl_xor(v, 2, 64);
        v += __shfl_xor(v, 4, 64);
        v += __shfl_xor(v, 8, 64);
        rs[i] = v;
    }
    if (rp == 0) {
        const int slab = jc * 2 + (wave >> 1);        // col-half gets own slab
        const int rowb = bi * 128 + wr + q * 4;
        #pragma unroll
        for (int rt = 0; rt < 4; ++rt)
            #pragma unroll
            for (int r = 0; r < 4; ++r)
                rspart[slab * TWO_N + rowb + rt * 16 + r] = rs[rt * 4 + r];
    }
}

__global__ __launch_bounds__(1024) void finalize_kernel(const float* __restrict__ rspart,
                                                        const float* __restrict__ pos,
                                                        float* __restrict__ out) {
    __shared__ float red[16];
    int tid = threadIdx.x;
    float local = 0.f;
    #pragma unroll
    for (int i = 0; i < TWO_N / 1024; ++i) {
        int k = i * 1024 + tid;
        float rsum = 0.f;
        #pragma unroll
        for (int p = 0; p < NPART; ++p) rsum += rspart[p * TWO_N + k];
        float ps = pos[k & (NPAIR - 1)];
        float p2 = ps + ps;
        float denom = rsum + __expf(p2);
        local += logf(denom) - p2;
    }
    #pragma unroll
    for (int m = 1; m < 64; m <<= 1) local += __shfl_xor(local, m, 64);
    if ((tid & 63) == 0) red[tid >> 6] = local;
    __syncthreads();
    if (tid == 0) {
        float s = 0.f;
        #pragma unroll
        for (int w = 0; w < 16; ++w) s += red[w];
        out[0] = s / (float)TWO_N;
    }
}

extern "C" void kernel_launch(void* const* d_in, const int* in_sizes, int n_in,
                              void* d_out, int out_size, void* d_ws, size_t ws_size,
                              hipStream_t stream) {
    const float* zi = (const float*)d_in[0];
    const float* zj = (const float*)d_in[1];
    char* ws = (char*)d_ws;
    unsigned int* Rb = (unsigned int*)ws;                           // 2 MB bf16 rows
    float* rspart = (float*)(ws + 2 * 1024 * 1024);                 // 16*8192*4 = 512 KB
    float* pos = (float*)(ws + 2 * 1024 * 1024 + 512 * 1024);       // 16 KB

    norm_kernel<<<NPAIR / 4, 256, 0, stream>>>(zi, zj, Rb, pos);
    simexp_kernel<<<64 * NJC, 256, 0, stream>>>((const uint4*)Rb, rspart);
    finalize_kernel<<<1, 1024, 0, stream>>>(rspart, pos, (float*)d_out);
}

// Round 4
// 86.256 us; speedup vs baseline: 1.8004x; 1.0710x over previous
//
#include <hip/hip_runtime.h>
#include <hip/hip_bf16.h>
#include <math.h>

#define NPAIR 4096       // N = B*S
#define D 128
#define TWO_N 8192
#define NJC 8            // col-slab splits; each block covers 1024 cols
#define NPART (NJC * 2)  // two col-half waves per block store separately

typedef short bf16x8 __attribute__((ext_vector_type(8)));
typedef float f32x4 __attribute__((ext_vector_type(4)));

__device__ __forceinline__ void async_ld16(void* lds, const void* g) {
    // async global->LDS DMA, 16B per lane; LDS dest = wave-uniform base + lane*16
    __builtin_amdgcn_global_load_lds(
        (__attribute__((address_space(1))) const unsigned int*)g,
        (__attribute__((address_space(3))) unsigned int*)lds, 16, 0, 0);
}

__device__ inline unsigned short f2bf(float x) {
    union { float f; unsigned u; } v; v.f = x;
    unsigned u = v.u;
    unsigned r = u + 0x7fffu + ((u >> 16) & 1u);   // round-to-nearest-even
    return (unsigned short)(r >> 16);
}

// 1024 blocks x 256 threads; wave w handles pair-row k = blockIdx*4 + w.
// Also zero-inits out[0] (finalize accumulates into it atomically).
__global__ __launch_bounds__(256) void norm_kernel(const float* __restrict__ zi,
                                                   const float* __restrict__ zj,
                                                   unsigned int* __restrict__ Rb,
                                                   float* __restrict__ pos,
                                                   float* __restrict__ out) {
    if (blockIdx.x == 0 && threadIdx.x == 0) out[0] = 0.f;
    int k = blockIdx.x * 4 + (threadIdx.x >> 6);
    int t = threadIdx.x & 63;                 // 2 elems each
    const float2 a = *(const float2*)(zi + k * D + 2 * t);
    const float2 b = *(const float2*)(zj + k * D + 2 * t);
    float si = a.x * a.x + a.y * a.y;
    float sj = b.x * b.x + b.y * b.y;
    float dt = a.x * b.x + a.y * b.y;
    #pragma unroll
    for (int m = 1; m < 64; m <<= 1) {
        si += __shfl_xor(si, m, 64);
        sj += __shfl_xor(sj, m, 64);
        dt += __shfl_xor(dt, m, 64);
    }
    float ii = 1.0f / fmaxf(sqrtf(si), 1e-12f);
    float ij = 1.0f / fmaxf(sqrtf(sj), 1e-12f);
    unsigned short b0 = f2bf(a.x * ii), b1 = f2bf(a.y * ii);
    Rb[k * (D / 2) + t] = (unsigned)b0 | ((unsigned)b1 << 16);
    b0 = f2bf(b.x * ij); b1 = f2bf(b.y * ij);
    Rb[(k + NPAIR) * (D / 2) + t] = (unsigned)b0 | ((unsigned)b1 << 16);
    if (t == 0) pos[k] = dt * ii * ij;
}

// 512 blocks: bi = b>>3 (row stripe of 128), jc = b&7 (col slab of 1024).
// A fragments live in registers (loaded once); B tiles stream through a
// 2x32KB LDS double buffer via async global_load_lds, prefetched one jt
// ahead (issued right after the barrier -> full compute phase in flight).
// Global gather is XOR-swizzled (chunk = rp ^ (row&15)) so the row-major
// LDS deposit gives 2-way (free) bank aliasing on the b128 fragment reads.
__global__ __launch_bounds__(256, 2) void simexp_kernel(const uint4* __restrict__ Rb,
                                                        float* __restrict__ rspart) {
    __shared__ uint4 Bs[2][2048];        // [buf][row*16 + j]; 32KB each
    const int bi = blockIdx.x >> 3, jc = blockIdx.x & 7;
    const int tid = threadIdx.x;
    const int wave = tid >> 6, lane = tid & 63;
    const int rp = lane & 15, q = lane >> 4;
    const int wr = (wave & 1) * 64;      // row quadrant
    const int wc = (wave >> 1) * 64;     // col quadrant

    // ---- A fragments -> registers: row = bi*128 + wr + rt*16 + rp, chunk = kt*4+q
    bf16x8 afr[4][4];                    // [kt][rt]
    {
        const uint4* Ab = Rb + (bi * 128 + wr + rp) * 16;
        #pragma unroll
        for (int kt = 0; kt < 4; ++kt)
            #pragma unroll
            for (int rt = 0; rt < 4; ++rt)
                afr[kt][rt] = *(const bf16x8*)&Ab[rt * 256 + kt * 4 + q];
    }

    // ---- B staging geometry (per-lane invariants) ----
    // issue 'it' of wave w covers rows rowbase..rowbase+3, rowbase=(it*4+w)*4.
    // lane L: row_local = rowbase + q, j = rp; row_local & 15 == w*4 + q.
    const int rl15 = wave * 4 + q;                       // row_local & 15
    const int laneoff = rl15 * 256 + ((rp ^ rl15) << 4); // byte off within 4KB it-slab
    const char* Rbb = (const char*)Rb;

    float rs[16];
    #pragma unroll
    for (int i = 0; i < 16; ++i) rs[i] = 0.f;

    // prefetch jt=0
    {
        const char* g = Rbb + (jc * 1024) * 256 + laneoff;
        char* l = (char*)&Bs[0][0] + wave * 1024;
        #pragma unroll
        for (int it = 0; it < 8; ++it)
            async_ld16(l + it * 4096, g + it * 4096);
    }

    for (int jt = 0; jt < 8; ++jt) {
        __syncthreads();   // compiler emits vmcnt(0): drains own prefetch of jt

        if (jt < 7) {      // issue prefetch jt+1 now; lands during compute of jt
            const char* g = Rbb + (jc * 1024 + (jt + 1) * 128) * 256 + laneoff;
            char* l = (char*)&Bs[(jt + 1) & 1][0] + wave * 1024;
            #pragma unroll
            for (int it = 0; it < 8; ++it)
                async_ld16(l + it * 4096, g + it * 4096);
        }

        const uint4* B = &Bs[jt & 1][0];
        f32x4 acc[4][4] = {};
        #pragma unroll
        for (int kt = 0; kt < 4; ++kt) {
            const int k = kt * 4 + q;
            bf16x8 bfr[4];
            #pragma unroll
            for (int ct = 0; ct < 4; ++ct) {
                const int crow = wc + ct * 16 + rp;       // crow & 15 == rp
                bfr[ct] = *(const bf16x8*)&B[crow * 16 + (k ^ rp)];
            }
            #pragma unroll
            for (int rt = 0; rt < 4; ++rt)
                #pragma unroll
                for (int ct = 0; ct < 4; ++ct)
                    acc[rt][ct] = __builtin_amdgcn_mfma_f32_16x16x32_bf16(
                        afr[kt][rt], bfr[ct], acc[rt][ct], 0, 0, 0);
        }

        // D layout: col = lane&15 (rp), row = q*4 + reg
        if (jc * 1024 + jt * 128 == bi * 128) {   // diagonal tile (wave-uniform)
            #pragma unroll
            for (int rt = 0; rt < 4; ++rt)
                #pragma unroll
                for (int r = 0; r < 4; ++r) {
                    int ro = wr + q * 4 + rt * 16 + r;    // stripe-local row
                    float s = 0.f;
                    #pragma unroll
                    for (int ct = 0; ct < 4; ++ct) {
                        int co = wc + ct * 16 + rp;
                        float x = acc[rt][ct][r];
                        float e = __expf(x + x);
                        s += (ro == co) ? 0.f : e;
                    }
                    rs[rt * 4 + r] += s;
                }
        } else {
            #pragma unroll
            for (int rt = 0; rt < 4; ++rt)
                #pragma unroll
                for (int r = 0; r < 4; ++r) {
                    float s = 0.f;
                    #pragma unroll
                    for (int ct = 0; ct < 4; ++ct) {
                        float x = acc[rt][ct][r];
                        s += __expf(x + x);
                    }
                    rs[rt * 4 + r] += s;
                }
        }
    }

    // Once per block: reduce each reg across the 16 rp lanes, store.
    #pragma unroll
    for (int i = 0; i < 16; ++i) {
        float v = rs[i];
        v += __shfl_xor(v, 1, 64);
        v += __shfl_xor(v, 2, 64);
        v += __shfl_xor(v, 4, 64);
        v += __shfl_xor(v, 8, 64);
        rs[i] = v;
    }
    if (rp == 0) {
        const int slab = jc * 2 + (wave >> 1);    // col-half gets own slab
        const int rowb = bi * 128 + wr + q * 4;
        #pragma unroll
        for (int rt = 0; rt < 4; ++rt)
            #pragma unroll
            for (int r = 0; r < 4; ++r)
                rspart[slab * TWO_N + rowb + rt * 16 + r] = rs[rt * 4 + r];
    }
}

// 16 blocks x 256 threads; each thread does 2 rows; one atomicAdd per block.
__global__ __launch_bounds__(256) void finalize_kernel(const float* __restrict__ rspart,
                                                       const float* __restrict__ pos,
                                                       float* __restrict__ out) {
    __shared__ float red[4];
    int tid = threadIdx.x;
    float local = 0.f;
    #pragma unroll
    for (int i = 0; i < 2; ++i) {
        int k = blockIdx.x * 512 + i * 256 + tid;
        float rsum = 0.f;
        #pragma unroll
        for (int p = 0; p < NPART; ++p) rsum += rspart[p * TWO_N + k];
        float ps = pos[k & (NPAIR - 1)];
        float p2 = ps + ps;
        local += logf(rsum + __expf(p2)) - p2;
    }
    #pragma unroll
    for (int m = 1; m < 64; m <<= 1) local += __shfl_xor(local, m, 64);
    if ((tid & 63) == 0) red[tid >> 6] = local;
    __syncthreads();
    if (tid == 0) {
        float s = red[0] + red[1] + red[2] + red[3];
        atomicAdd(out, s * (1.0f / (float)TWO_N));
    }
}

extern "C" void kernel_launch(void* const* d_in, const int* in_sizes, int n_in,
                              void* d_out, int out_size, void* d_ws, size_t ws_size,
                              hipStream_t stream) {
    const float* zi = (const float*)d_in[0];
    const float* zj = (const float*)d_in[1];
    char* ws = (char*)d_ws;
    unsigned int* Rb = (unsigned int*)ws;                           // 2 MB bf16 rows
    float* rspart = (float*)(ws + 2 * 1024 * 1024);                 // 16*8192*4 = 512 KB
    float* pos = (float*)(ws + 2 * 1024 * 1024 + 512 * 1024);       // 16 KB

    norm_kernel<<<NPAIR / 4, 256, 0, stream>>>(zi, zj, Rb, pos, (float*)d_out);
    simexp_kernel<<<64 * NJC, 256, 0, stream>>>((const uint4*)Rb, rspart);
    finalize_kernel<<<16, 256, 0, stream>>>(rspart, pos, (float*)d_out);
}